// Round 1
// baseline (2099.872 us; speedup 1.0000x reference)
//
#include <hip/hip_runtime.h>
#include <cfloat>
#include <cmath>

#define E      512
#define FOURE  2048
#define VT     50000
#define SLEN   128
#define TLEN   129            // decoder steps (targets + EOS)
#define NSTEPS 257
#define NB     64             // persistent LSTM blocks (<=256 CUs -> co-resident)
#define NCHUNK 196            // ceil(50000 / 256 cols-per-block)
#define TPAD   132

// ---- workspace layout (bytes) ----
#define BAR_OFF    0            // 257 * 16 u32 (64B stride)  = 16448
#define HB_OFF     16448        // h double buffer 2*512 f32  = 4096
#define ZERO_BYTES 20544        // memset region: barriers + h buffers
#define HALL_OFF   20544        // 129*512 f32 = 264192
#define GXE_OFF    284736       // 128*2048 f32 = 1048576
#define GXD_OFF    1333312      // 129*2048 f32 = 1056768
#define PM_OFF     2390080      // 196*132 f32 = 103488
#define PS_OFF     2493568      // 196*132 f32 = 103488
#define TL_OFF     2597056      // 129 f32

__device__ __forceinline__ float sigf(float x){ return 1.0f/(1.0f+__expf(-x)); }

// =================== A: Gx[t][r] = x_t @ W_ih^T + b_ih + b_hh ===================
// grid (33, 8): tiles 0..15 encoder (t0=tile*8), 16..32 decoder. block 256.
__global__ __launch_bounds__(256) void gx_kernel(
    const int* __restrict__ src, const int* __restrict__ tgt,
    const float* __restrict__ Wx, const float* __restrict__ Wy,
    const float* __restrict__ encWih, const float* __restrict__ encBih, const float* __restrict__ encBhh,
    const float* __restrict__ decWih, const float* __restrict__ decBih, const float* __restrict__ decBhh,
    float* __restrict__ GxE, float* __restrict__ GxD)
{
  __shared__ float xs[8][E];
  const int tid  = threadIdx.x;
  const int tile = blockIdx.x;
  const bool is_dec = tile >= 16;
  const int t0 = is_dec ? (tile-16)*8 : tile*8;
  const int T  = is_dec ? TLEN : SLEN;

  for (int tt=0; tt<8; ++tt){
    int t = t0+tt;
    if (t < T){
      const float* xrow;
      if (is_dec) xrow = (t==0) ? (Wx + (size_t)1*E) : (Wy + (size_t)tgt[t-1]*E);
      else        xrow = Wx + (size_t)src[t]*E;
      xs[tt][tid]     = xrow[tid];
      xs[tt][tid+256] = xrow[tid+256];
    }
  }
  __syncthreads();

  const int r = blockIdx.y*256 + tid;
  const float* wrow = (is_dec ? decWih : encWih) + (size_t)r*E;
  const float  bias = is_dec ? (decBih[r]+decBhh[r]) : (encBih[r]+encBhh[r]);
  float acc[8];
  #pragma unroll
  for (int i=0;i<8;++i) acc[i]=0.f;

  for (int kc=0; kc<E; kc+=4){
    float4 w = *(const float4*)(wrow+kc);
    #pragma unroll
    for (int tt=0; tt<8; ++tt){
      float4 x = *(const float4*)&xs[tt][kc];   // uniform addr -> LDS broadcast
      acc[tt] += w.x*x.x + w.y*x.y + w.z*x.z + w.w*x.w;
    }
  }
  float* Gx = is_dec ? GxD : GxE;
  #pragma unroll
  for (int tt=0; tt<8; ++tt){
    int t = t0+tt;
    if (t < T) Gx[(size_t)t*FOURE + r] = bias + acc[tt];
  }
}

// =================== B: persistent sequential LSTM ===================
__device__ __forceinline__ void grid_barrier(unsigned* ctr){
  __syncthreads();                         // block stores drained (vmcnt 0)
  if (threadIdx.x == 0){
    __threadfence();                       // agent release (L2 writeback)
    __hip_atomic_fetch_add(ctr, 1u, __ATOMIC_RELAXED, __HIP_MEMORY_SCOPE_AGENT);
    while (__hip_atomic_load(ctr, __ATOMIC_RELAXED, __HIP_MEMORY_SCOPE_AGENT) < (unsigned)NB)
      __builtin_amdgcn_s_sleep(1);
    __threadfence();                       // agent acquire (L1/L2 invalidate)
  }
  __syncthreads();
}

__device__ __forceinline__ void lstm_step(
    const float4 (&W)[16], const float* __restrict__ Gx, int tloc, int step, bool isdec,
    int k0, int r, int gate, bool writer, int j,
    float& c, float* hb, float* h_all, unsigned* bar)
{
  const float4* h4p = (const float4*)(hb + ((size_t)(step&1))*E + k0);
  float gx = Gx[(size_t)tloc*FOURE + r];
  float acc = 0.f;
  #pragma unroll
  for (int i=0;i<16;++i){
    float4 h4 = h4p[i];
    acc += W[i].x*h4.x + W[i].y*h4.y + W[i].z*h4.z + W[i].w*h4.w;
  }
  // reduce over the 8 k-slice lanes (bits 0..2)
  acc += __shfl_xor(acc,1); acc += __shfl_xor(acc,2); acc += __shfl_xor(acc,4);
  float gv = acc + gx;
  // all-gather the 4 gate values within the 32-lane half (bits 3..4)
  float x1 = __shfl_xor(gv,8);
  float x2 = __shfl_xor(gv,16);
  float x3 = __shfl_xor(x1,16);
  float gi = (gate==0)?gv:(gate==1)?x1:(gate==2)?x2:x3;
  float gf = (gate==1)?gv:(gate==0)?x1:(gate==3)?x2:x3;
  float gg = (gate==2)?gv:(gate==3)?x1:(gate==0)?x2:x3;
  float go = (gate==3)?gv:(gate==2)?x1:(gate==1)?x2:x3;
  c = sigf(gf)*c + sigf(gi)*tanhf(gg);
  float hnew = sigf(go)*tanhf(c);
  if (writer){
    hb[((size_t)((step+1)&1))*E + j] = hnew;
    if (isdec) h_all[(size_t)tloc*E + j] = hnew;
  }
  grid_barrier(bar + (size_t)step*16);
}

__global__ __launch_bounds__(256, 1) void lstm_kernel(
    const float* __restrict__ GxE, const float* __restrict__ GxD,
    const float* __restrict__ encWhh, const float* __restrict__ decWhh,
    float* hb, float* h_all, unsigned* bar)
{
  const int tid  = threadIdx.x;
  const int wave = tid >> 6, lane = tid & 63;
  const int jj   = lane >> 5;
  const int gate = (lane >> 3) & 3;
  const int s    = lane & 7;
  const int j    = blockIdx.x*8 + wave*2 + jj;   // h element owned by this half-wave
  const int r    = gate*E + j;                   // gate row (torch order i,f,g,o)
  const int k0   = s*64;                         // this lane's 64-wide k slice
  const bool writer = (gate==0 && s==0);

  float4 we[16], wd[16];                         // recurrent weights, register-resident
  {
    const float4* e4 = (const float4*)(encWhh + (size_t)r*E + k0);
    const float4* d4 = (const float4*)(decWhh + (size_t)r*E + k0);
    #pragma unroll
    for (int i=0;i<16;++i){ we[i]=e4[i]; wd[i]=d4[i]; }
  }

  float c = 0.f;
  for (int step=0; step<SLEN; ++step)
    lstm_step(we, GxE, step, step, false, k0, r, gate, writer, j, c, hb, h_all, bar);
  c = 0.f;                                       // reference resets cell state before decoding
  for (int step=SLEN; step<NSTEPS; ++step)
    lstm_step(wd, GxD, step-SLEN, step, true, k0, r, gate, writer, j, c, hb, h_all, bar);
}

// =================== C1: logits GEMM + per-(t,chunk) softmax partials ===================
// grid (196 chunks, 5 t-tiles), block 128. Each thread: 2 columns, acc over 32 t's.
__global__ __launch_bounds__(128) void c1_kernel(
    const float* __restrict__ h_all, const float* __restrict__ W, const float* __restrict__ bvec,
    const int* __restrict__ tgt, float* __restrict__ pm, float* __restrict__ ps, float* __restrict__ tl)
{
  __shared__ float hst[32][E];                   // exactly 64 KiB
  const int tid  = threadIdx.x;
  const int wv   = tid >> 6, lane = tid & 63;
  const int chunk = blockIdx.x;
  const int t0    = blockIdx.y * 32;
  const int nt    = (t0 + 32 <= TLEN) ? 32 : (TLEN - t0);

  for (int idx = tid; idx < nt*(E/4); idx += 128)
    ((float4*)&hst[0][0])[idx] = ((const float4*)(h_all + (size_t)t0*E))[idx];
  __syncthreads();

  const int c0 = chunk*256 + tid;
  const int c1 = c0 + 128;
  const bool v0 = c0 < VT, v1 = c1 < VT;
  const float* w0 = W + (size_t)(v0 ? c0 : 0)*E;
  const float* w1 = W + (size_t)(v1 ? c1 : 0)*E;

  float acc0[32], acc1[32];
  #pragma unroll
  for (int i=0;i<32;++i){ acc0[i]=0.f; acc1[i]=0.f; }

  for (int kc=0; kc<E; kc+=4){
    float4 wa = *(const float4*)(w0+kc);
    float4 wb = *(const float4*)(w1+kc);
    #pragma unroll
    for (int tt=0; tt<32; ++tt){
      float4 h4 = *(const float4*)&hst[tt][kc];  // uniform addr -> LDS broadcast
      acc0[tt] += wa.x*h4.x + wa.y*h4.y + wa.z*h4.z + wa.w*h4.w;
      acc1[tt] += wb.x*h4.x + wb.y*h4.y + wb.z*h4.z + wb.w*h4.w;
    }
  }
  const float b0 = v0 ? bvec[c0] : 0.f;
  const float b1 = v1 ? bvec[c1] : 0.f;

  __syncthreads();                               // hst dead; alias its front as reduce scratch
  float* red = &hst[0][0];                       // [0,1]=max per wave, [2,3]=sum per wave

  #pragma unroll
  for (int tt=0; tt<32; ++tt){
    const bool act = tt < nt;
    float x0 = v0 ? acc0[tt]+b0 : -FLT_MAX;
    float x1 = v1 ? acc1[tt]+b1 : -FLT_MAX;
    float mx = fmaxf(x0,x1);
    #pragma unroll
    for (int off=1; off<64; off<<=1) mx = fmaxf(mx, __shfl_xor(mx, off));
    if (lane==0) red[wv] = mx;
    __syncthreads();
    mx = fmaxf(red[0], red[1]);
    float e = (v0 ? __expf(x0-mx) : 0.f) + (v1 ? __expf(x1-mx) : 0.f);
    #pragma unroll
    for (int off=1; off<64; off<<=1) e += __shfl_xor(e, off);
    if (lane==0) red[2+wv] = e;
    __syncthreads();
    float ssum = red[2] + red[3];
    if (act){
      int t = t0 + tt;
      if (tid==0){ pm[(size_t)chunk*TPAD + t] = mx; ps[(size_t)chunk*TPAD + t] = ssum; }
      int tok = (t < SLEN) ? tgt[t] : 1;         // appended EOS target
      if (v0 && c0==tok) tl[t] = x0;
      if (v1 && c1==tok) tl[t] = x1;
    }
    __syncthreads();
  }
}

// =================== C2: combine partials -> per-t loss -> sum ===================
__global__ __launch_bounds__(256) void c2_kernel(
    const float* __restrict__ pm, const float* __restrict__ ps, const float* __restrict__ tl,
    float* __restrict__ out)
{
  const int tid = threadIdx.x;
  float loss = 0.f;
  if (tid < TLEN){
    float m = -FLT_MAX, ssum = 0.f;
    for (int ch=0; ch<NCHUNK; ++ch){
      float mc = pm[(size_t)ch*TPAD + tid];
      float sc = ps[(size_t)ch*TPAD + tid];
      float nm = fmaxf(m, mc);
      ssum = ssum*__expf(m-nm) + sc*__expf(mc-nm);
      m = nm;
    }
    loss = (m + __logf(ssum)) - tl[tid];
  }
  __shared__ float red[4];
  #pragma unroll
  for (int off=1; off<64; off<<=1) loss += __shfl_xor(loss, off);
  if ((tid & 63)==0) red[tid>>6] = loss;
  __syncthreads();
  if (tid==0) out[0] = red[0]+red[1]+red[2]+red[3];
}

// =================== launch ===================
extern "C" void kernel_launch(void* const* d_in, const int* in_sizes, int n_in,
                              void* d_out, int out_size, void* d_ws, size_t ws_size,
                              hipStream_t stream)
{
  const int*   src    = (const int*)  d_in[0];
  const int*   tgt    = (const int*)  d_in[1];
  const float* Wx     = (const float*)d_in[2];
  const float* Wy     = (const float*)d_in[3];
  const float* encWih = (const float*)d_in[4];
  const float* encWhh = (const float*)d_in[5];
  const float* encBih = (const float*)d_in[6];
  const float* encBhh = (const float*)d_in[7];
  const float* decWih = (const float*)d_in[8];
  const float* decWhh = (const float*)d_in[9];
  const float* decBih = (const float*)d_in[10];
  const float* decBhh = (const float*)d_in[11];
  const float* Whr    = (const float*)d_in[12];
  const float* bhr    = (const float*)d_in[13];

  char* ws = (char*)d_ws;
  unsigned* bar = (unsigned*)(ws + BAR_OFF);
  float* hb     = (float*)(ws + HB_OFF);
  float* hall   = (float*)(ws + HALL_OFF);
  float* GxE    = (float*)(ws + GXE_OFF);
  float* GxD    = (float*)(ws + GXD_OFF);
  float* pm     = (float*)(ws + PM_OFF);
  float* ps     = (float*)(ws + PS_OFF);
  float* tl     = (float*)(ws + TL_OFF);

  hipMemsetAsync(ws, 0, ZERO_BYTES, stream);     // reset barriers + h0=0 each call

  dim3 ggrid(33, 8);
  gx_kernel<<<ggrid, 256, 0, stream>>>(src, tgt, Wx, Wy,
      encWih, encBih, encBhh, decWih, decBih, decBhh, GxE, GxD);

  lstm_kernel<<<NB, 256, 0, stream>>>(GxE, GxD, encWhh, decWhh, hb, hall, bar);

  dim3 cgrid(NCHUNK, 5);
  c1_kernel<<<cgrid, 128, 0, stream>>>(hall, Whr, bhr, tgt, pm, ps, tl);

  c2_kernel<<<1, 256, 0, stream>>>(pm, ps, tl, (float*)d_out);
}

// Round 2
// 1705.011 us; speedup vs baseline: 1.2316x; 1.2316x over previous
//
#include <hip/hip_runtime.h>
#include <cfloat>
#include <cmath>

#define E      512
#define FOURE  2048
#define VT     50000
#define SLEN   128
#define TLEN   129            // decoder steps (targets + EOS)
#define NSTEPS 257
#define NB     64             // persistent LSTM blocks (<=256 CUs -> co-resident)
#define NCHUNK 196            // ceil(50000 / 256 cols-per-block)
#define TPAD   132

// ---- workspace layout (bytes) ----
#define FLAGS_OFF  0            // 64 flags, 128B stride      = 8192
#define HB_OFF     8192         // h double buffer 2*256 u64  = 4096
#define ZERO_BYTES 12288        // memset region: flags + h buffers
#define HALL_OFF   12288        // 129*512 f32 = 264192
#define GXE_OFF    276480       // 128*2048 f32 = 1048576
#define GXD_OFF    1325056      // 129*2048 f32 = 1056768
#define PM_OFF     2381824      // 196*132 f32 = 103488
#define PS_OFF     2485312      // 196*132 f32 = 103488
#define TL_OFF     2588800      // 129 f32

#define KEEP4(v) asm volatile("" : "+v"((v).x), "+v"((v).y), "+v"((v).z), "+v"((v).w))

__device__ __forceinline__ float sigf(float x){ return 1.0f/(1.0f+__expf(-x)); }
__device__ __forceinline__ float tanhf_fast(float x){ return 2.f*sigf(2.f*x) - 1.f; }

// =================== A: Gx[t][r] = x_t @ W_ih^T + b_ih + b_hh ===================
__global__ __launch_bounds__(256) void gx_kernel(
    const int* __restrict__ src, const int* __restrict__ tgt,
    const float* __restrict__ Wx, const float* __restrict__ Wy,
    const float* __restrict__ encWih, const float* __restrict__ encBih, const float* __restrict__ encBhh,
    const float* __restrict__ decWih, const float* __restrict__ decBih, const float* __restrict__ decBhh,
    float* __restrict__ GxE, float* __restrict__ GxD)
{
  __shared__ float xs[8][E];
  const int tid  = threadIdx.x;
  const int tile = blockIdx.x;
  const bool is_dec = tile >= 16;
  const int t0 = is_dec ? (tile-16)*8 : tile*8;
  const int T  = is_dec ? TLEN : SLEN;

  for (int tt=0; tt<8; ++tt){
    int t = t0+tt;
    if (t < T){
      const float* xrow;
      if (is_dec) xrow = (t==0) ? (Wx + (size_t)1*E) : (Wy + (size_t)tgt[t-1]*E);
      else        xrow = Wx + (size_t)src[t]*E;
      xs[tt][tid]     = xrow[tid];
      xs[tt][tid+256] = xrow[tid+256];
    }
  }
  __syncthreads();

  const int r = blockIdx.y*256 + tid;
  const float* wrow = (is_dec ? decWih : encWih) + (size_t)r*E;
  const float  bias = is_dec ? (decBih[r]+decBhh[r]) : (encBih[r]+encBhh[r]);
  float acc[8];
  #pragma unroll
  for (int i=0;i<8;++i) acc[i]=0.f;

  for (int kc=0; kc<E; kc+=4){
    float4 w = *(const float4*)(wrow+kc);
    #pragma unroll
    for (int tt=0; tt<8; ++tt){
      float4 x = *(const float4*)&xs[tt][kc];
      acc[tt] += w.x*x.x + w.y*x.y + w.z*x.z + w.w*x.w;
    }
  }
  float* Gx = is_dec ? GxD : GxE;
  #pragma unroll
  for (int tt=0; tt<8; ++tt){
    int t = t0+tt;
    if (t < T) Gx[(size_t)t*FOURE + r] = bias + acc[tt];
  }
}

// =================== B: persistent sequential LSTM (fence-free) ===================
// h transferred via agent-scope relaxed 8B atomics (cache-bypassing, coherent
// cross-XCD without fences). Barrier: per-block tagged flags; wave 0 of every
// block polls all 64 flags in parallel. __syncthreads() between the h atomic
// stores and the flag store provides ordering (it drains vmcnt per wave).
__device__ __forceinline__ void lstm_step(
    const float4 (&w)[16], const float* __restrict__ Gx, int tloc, int step, bool isdec,
    int k0, int r, int gate, int lane, int wave, int bid, int s, int j,
    float& c, unsigned long long* hb64, float* h_all, unsigned* flags)
{
  float gx = Gx[(size_t)tloc*FOURE + r];

  unsigned long long* hp = hb64 + ((size_t)(step&1))*256 + (k0>>1);
  unsigned long long hu[32];
  #pragma unroll
  for (int i=0;i<32;++i)
    hu[i] = __hip_atomic_load(hp+i, __ATOMIC_RELAXED, __HIP_MEMORY_SCOPE_AGENT);

  float acc = 0.f;
  #pragma unroll
  for (int i=0;i<16;++i){
    acc += w[i].x*__uint_as_float((unsigned)hu[2*i]);
    acc += w[i].y*__uint_as_float((unsigned)(hu[2*i]>>32));
    acc += w[i].z*__uint_as_float((unsigned)hu[2*i+1]);
    acc += w[i].w*__uint_as_float((unsigned)(hu[2*i+1]>>32));
  }
  // reduce over the 8 k-slice lanes (bits 0..2)
  acc += __shfl_xor(acc,1); acc += __shfl_xor(acc,2); acc += __shfl_xor(acc,4);
  float gv = acc + gx;
  // all-gather the 4 gate values within the 32-lane half (bits 3..4)
  float x1 = __shfl_xor(gv,8);
  float x2 = __shfl_xor(gv,16);
  float x3 = __shfl_xor(x1,16);
  float gi = (gate==0)?gv:(gate==1)?x1:(gate==2)?x2:x3;
  float gf = (gate==1)?gv:(gate==0)?x1:(gate==3)?x2:x3;
  float gg = (gate==2)?gv:(gate==3)?x1:(gate==0)?x2:x3;
  float go = (gate==3)?gv:(gate==2)?x1:(gate==1)?x2:x3;
  c = sigf(gf)*c + sigf(gi)*tanhf_fast(gg);
  float hnew = sigf(go)*tanhf_fast(c);

  if (isdec && gate==0 && s==0) h_all[(size_t)tloc*E + j] = hnew;

  float hother = __shfl(hnew, 32);           // jj=1 half-wave's h value
  if (lane==0){
    unsigned long long pk = ((unsigned long long)__float_as_uint(hother)<<32)
                          |  (unsigned long long)__float_as_uint(hnew);
    __hip_atomic_store(hb64 + ((size_t)((step+1)&1))*256 + (bid*4 + wave), pk,
                       __ATOMIC_RELAXED, __HIP_MEMORY_SCOPE_AGENT);
  }

  __syncthreads();                           // drains all waves' vmem (stores acked)
  const unsigned tag = (unsigned)(step+1);
  if (wave==0){
    if (lane==0)
      __hip_atomic_store(&flags[bid*32], tag, __ATOMIC_RELAXED, __HIP_MEMORY_SCOPE_AGENT);
    while (__hip_atomic_load(&flags[lane*32], __ATOMIC_RELAXED, __HIP_MEMORY_SCOPE_AGENT) < tag)
      __builtin_amdgcn_s_sleep(1);
  }
  __syncthreads();
}

__global__ __launch_bounds__(256, 1) void lstm_kernel(
    const float* __restrict__ GxE, const float* __restrict__ GxD,
    const float* __restrict__ encWhh, const float* __restrict__ decWhh,
    unsigned long long* hb64, float* h_all, unsigned* flags)
{
  const int tid  = threadIdx.x;
  const int bid  = blockIdx.x;
  const int wave = tid >> 6, lane = tid & 63;
  const int jj   = lane >> 5;
  const int gate = (lane >> 3) & 3;
  const int s    = lane & 7;
  const int j    = bid*8 + wave*2 + jj;      // h element owned by this half-wave
  const int r    = gate*E + j;               // gate row (torch order i,f,g,o)
  const int k0   = s*64;                     // this lane's 64-wide k slice

  float4 w[16];                              // one phase's weights, VGPR-pinned
  {
    const float4* e4 = (const float4*)(encWhh + (size_t)r*E + k0);
    #pragma unroll
    for (int i=0;i<16;++i){ w[i]=e4[i]; KEEP4(w[i]); }
  }
  float c = 0.f;
  for (int step=0; step<SLEN; ++step)
    lstm_step(w, GxE, step, step, false, k0, r, gate, lane, wave, bid, s, j, c, hb64, h_all, flags);

  {
    const float4* d4 = (const float4*)(decWhh + (size_t)r*E + k0);
    #pragma unroll
    for (int i=0;i<16;++i){ w[i]=d4[i]; KEEP4(w[i]); }
  }
  c = 0.f;                                   // reference resets cell state before decoding
  for (int step=SLEN; step<NSTEPS; ++step)
    lstm_step(w, GxD, step-SLEN, step, true, k0, r, gate, lane, wave, bid, s, j, c, hb64, h_all, flags);
}

// =================== C1: logits GEMM + per-(t,chunk) softmax partials ===================
__global__ __launch_bounds__(128) void c1_kernel(
    const float* __restrict__ h_all, const float* __restrict__ W, const float* __restrict__ bvec,
    const int* __restrict__ tgt, float* __restrict__ pm, float* __restrict__ ps, float* __restrict__ tl)
{
  __shared__ float hst[32][E];               // exactly 64 KiB
  const int tid  = threadIdx.x;
  const int wv   = tid >> 6, lane = tid & 63;
  const int chunk = blockIdx.x;
  const int t0    = blockIdx.y * 32;
  const int nt    = (t0 + 32 <= TLEN) ? 32 : (TLEN - t0);

  for (int idx = tid; idx < nt*(E/4); idx += 128)
    ((float4*)&hst[0][0])[idx] = ((const float4*)(h_all + (size_t)t0*E))[idx];
  __syncthreads();

  const int c0 = chunk*256 + tid;
  const int c1 = c0 + 128;
  const bool v0 = c0 < VT, v1 = c1 < VT;
  const float* w0 = W + (size_t)(v0 ? c0 : 0)*E;
  const float* w1 = W + (size_t)(v1 ? c1 : 0)*E;

  float acc0[32], acc1[32];
  #pragma unroll
  for (int i=0;i<32;++i){ acc0[i]=0.f; acc1[i]=0.f; }

  for (int kc=0; kc<E; kc+=4){
    float4 wa = *(const float4*)(w0+kc);
    float4 wb = *(const float4*)(w1+kc);
    #pragma unroll
    for (int tt=0; tt<32; ++tt){
      float4 h4 = *(const float4*)&hst[tt][kc];
      acc0[tt] += wa.x*h4.x + wa.y*h4.y + wa.z*h4.z + wa.w*h4.w;
      acc1[tt] += wb.x*h4.x + wb.y*h4.y + wb.z*h4.z + wb.w*h4.w;
    }
  }
  const float b0 = v0 ? bvec[c0] : 0.f;
  const float b1 = v1 ? bvec[c1] : 0.f;

  __syncthreads();                           // hst dead; alias front as reduce scratch
  float* red = &hst[0][0];

  #pragma unroll
  for (int tt=0; tt<32; ++tt){
    const bool act = tt < nt;
    float x0 = v0 ? acc0[tt]+b0 : -FLT_MAX;
    float x1 = v1 ? acc1[tt]+b1 : -FLT_MAX;
    float mx = fmaxf(x0,x1);
    #pragma unroll
    for (int off=1; off<64; off<<=1) mx = fmaxf(mx, __shfl_xor(mx, off));
    if (lane==0) red[wv] = mx;
    __syncthreads();
    mx = fmaxf(red[0], red[1]);
    float e = (v0 ? __expf(x0-mx) : 0.f) + (v1 ? __expf(x1-mx) : 0.f);
    #pragma unroll
    for (int off=1; off<64; off<<=1) e += __shfl_xor(e, off);
    if (lane==0) red[2+wv] = e;
    __syncthreads();
    float ssum = red[2] + red[3];
    if (act){
      int t = t0 + tt;
      if (tid==0){ pm[(size_t)chunk*TPAD + t] = mx; ps[(size_t)chunk*TPAD + t] = ssum; }
      int tok = (t < SLEN) ? tgt[t] : 1;
      if (v0 && c0==tok) tl[t] = x0;
      if (v1 && c1==tok) tl[t] = x1;
    }
    __syncthreads();
  }
}

// =================== C2: combine partials -> per-t loss -> sum ===================
__global__ __launch_bounds__(256) void c2_kernel(
    const float* __restrict__ pm, const float* __restrict__ ps, const float* __restrict__ tl,
    float* __restrict__ out)
{
  const int tid = threadIdx.x;
  float loss = 0.f;
  if (tid < TLEN){
    float m = -FLT_MAX, ssum = 0.f;
    for (int ch=0; ch<NCHUNK; ++ch){
      float mc = pm[(size_t)ch*TPAD + tid];
      float sc = ps[(size_t)ch*TPAD + tid];
      float nm = fmaxf(m, mc);
      ssum = ssum*__expf(m-nm) + sc*__expf(mc-nm);
      m = nm;
    }
    loss = (m + __logf(ssum)) - tl[tid];
  }
  __shared__ float red[4];
  #pragma unroll
  for (int off=1; off<64; off<<=1) loss += __shfl_xor(loss, off);
  if ((tid & 63)==0) red[tid>>6] = loss;
  __syncthreads();
  if (tid==0) out[0] = red[0]+red[1]+red[2]+red[3];
}

// =================== launch ===================
extern "C" void kernel_launch(void* const* d_in, const int* in_sizes, int n_in,
                              void* d_out, int out_size, void* d_ws, size_t ws_size,
                              hipStream_t stream)
{
  const int*   src    = (const int*)  d_in[0];
  const int*   tgt    = (const int*)  d_in[1];
  const float* Wx     = (const float*)d_in[2];
  const float* Wy     = (const float*)d_in[3];
  const float* encWih = (const float*)d_in[4];
  const float* encWhh = (const float*)d_in[5];
  const float* encBih = (const float*)d_in[6];
  const float* encBhh = (const float*)d_in[7];
  const float* decWih = (const float*)d_in[8];
  const float* decWhh = (const float*)d_in[9];
  const float* decBih = (const float*)d_in[10];
  const float* decBhh = (const float*)d_in[11];
  const float* Whr    = (const float*)d_in[12];
  const float* bhr    = (const float*)d_in[13];

  char* ws = (char*)d_ws;
  unsigned* flags = (unsigned*)(ws + FLAGS_OFF);
  unsigned long long* hb64 = (unsigned long long*)(ws + HB_OFF);
  float* hall   = (float*)(ws + HALL_OFF);
  float* GxE    = (float*)(ws + GXE_OFF);
  float* GxD    = (float*)(ws + GXD_OFF);
  float* pm     = (float*)(ws + PM_OFF);
  float* ps     = (float*)(ws + PS_OFF);
  float* tl     = (float*)(ws + TL_OFF);

  hipMemsetAsync(ws, 0, ZERO_BYTES, stream);   // reset flags + h0=0 each call

  dim3 ggrid(33, 8);
  gx_kernel<<<ggrid, 256, 0, stream>>>(src, tgt, Wx, Wy,
      encWih, encBih, encBhh, decWih, decBih, decBhh, GxE, GxD);

  lstm_kernel<<<NB, 256, 0, stream>>>(GxE, GxD, encWhh, decWhh, hb64, hall, flags);

  dim3 cgrid(NCHUNK, 5);
  c1_kernel<<<cgrid, 128, 0, stream>>>(hall, Whr, bhr, tgt, pm, ps, tl);

  c2_kernel<<<1, 256, 0, stream>>>(pm, ps, tl, (float*)d_out);
}